// Round 1
// baseline (1312.978 us; speedup 1.0000x reference)
//
#include <hip/hip_runtime.h>
#include <math.h>

#define DM 512
#define NH 8
#define HD 64
#define BB 4
#define SS 2048
#define MROWS (BB*SS)   // 8192

// ---------------------------------------------------------------------------
// GEMM: C = X @ W^T + bias.   X:[M,512] row-major, W:[512,512] row-major.
// C[m,n] = sum_k X[m,k]*W[n,k] + bias[n]  (both operands read along rows).
// OUT_MODE 0: write into head-split [B, H, S, 64] layout (n-tile == head).
// OUT_MODE 1: write plain [M, 512] row-major.
template<int OUT_MODE>
__global__ __launch_bounds__(256)
void gemm_xwt(const float* __restrict__ X, const float* __restrict__ W,
              const float* __restrict__ bias, float* __restrict__ C)
{
    const int m0 = blockIdx.y * 64;
    const int n0 = blockIdx.x * 64;
    const int t  = threadIdx.x;
    const int ty = t >> 4;          // 0..15
    const int tx = t & 15;          // 0..15
    const int lr = t >> 3;          // 0..31 (staging row)
    const int lc = (t & 7) << 2;    // 0,4,...,28 (staging col)

    __shared__ float Xs[32][68];    // k-major [BK][BM+pad], pad keeps b128 align
    __shared__ float Ws[32][68];

    float acc[4][4] = {{0.f,0.f,0.f,0.f},{0.f,0.f,0.f,0.f},
                       {0.f,0.f,0.f,0.f},{0.f,0.f,0.f,0.f}};

    for (int k0 = 0; k0 < DM; k0 += 32) {
        #pragma unroll
        for (int hh = 0; hh < 2; ++hh) {
            const int row = lr + hh*32;
            const float4 xv = *(const float4*)(X + (size_t)(m0+row)*DM + k0 + lc);
            Xs[lc+0][row] = xv.x; Xs[lc+1][row] = xv.y;
            Xs[lc+2][row] = xv.z; Xs[lc+3][row] = xv.w;
            const float4 wv = *(const float4*)(W + (size_t)(n0+row)*DM + k0 + lc);
            Ws[lc+0][row] = wv.x; Ws[lc+1][row] = wv.y;
            Ws[lc+2][row] = wv.z; Ws[lc+3][row] = wv.w;
        }
        __syncthreads();
        #pragma unroll
        for (int kk = 0; kk < 32; ++kk) {
            const float4 av = *(const float4*)&Xs[kk][ty<<2];
            const float4 bv = *(const float4*)&Ws[kk][tx<<2];
            const float a[4] = {av.x, av.y, av.z, av.w};
            const float b[4] = {bv.x, bv.y, bv.z, bv.w};
            #pragma unroll
            for (int i = 0; i < 4; ++i)
                #pragma unroll
                for (int j = 0; j < 4; ++j)
                    acc[i][j] += a[i]*b[j];
        }
        __syncthreads();
    }

    const int n = n0 + (tx<<2);
    const float4 bv4 = *(const float4*)(bias + n);
    #pragma unroll
    for (int i = 0; i < 4; ++i) {
        const int m = m0 + (ty<<2) + i;
        float4 r;
        r.x = acc[i][0] + bv4.x;
        r.y = acc[i][1] + bv4.y;
        r.z = acc[i][2] + bv4.z;
        r.w = acc[i][3] + bv4.w;
        if (OUT_MODE == 0) {
            const int b  = m >> 11;          // m / S
            const int s  = m & (SS-1);       // m % S
            const int h  = n0 >> 6;          // col tile == head
            const int d  = n - n0;
            *(float4*)(C + (((size_t)(b*NH + h)*SS + s) << 6) + d) = r;
        } else {
            *(float4*)(C + (size_t)m*DM + n) = r;
        }
    }
}

// ---------------------------------------------------------------------------
// Attention for one (b, h, 64-row q-tile).  Two-pass, score-storing:
//   pass 1: S = Q K^T / 8 -> write raw scores to attn buffer, online m/l.
//   pass 2: read scores back, p = exp(s-m)/l -> write final attn, O += p V.
__global__ __launch_bounds__(256)
void attn_kernel(const float* __restrict__ qp, const float* __restrict__ kp,
                 const float* __restrict__ vp, float* __restrict__ attn,
                 float* __restrict__ ctx)
{
    const int qt = blockIdx.x;      // 0..31
    const int h  = blockIdx.y;      // 0..7
    const int b  = blockIdx.z;      // 0..3
    const int q0 = qt * 64;
    const int t  = threadIdx.x;
    const int ty = t >> 4, tx = t & 15;
    const int r  = t >> 2;          // 0..63  (staging / pass-2 row mapping)
    const int c  = (t & 3) << 2;    // 0,4,8,12

    __shared__ float QP[64][68];    // pass1: Q (d-major) | pass2: P (j-major)
    __shared__ float SB[64][68];    // pass1: K (d-major) | pass2: V (row-major)
    __shared__ float m_s[64], il_s[64];

    const size_t headoff = (size_t)(b*NH + h) * SS * HD;
    const float* Qg = qp + headoff;
    const float* Kg = kp + headoff;
    const float* Vg = vp + headoff;
    float* attn_bh = attn + (size_t)(b*NH + h) * SS * SS;

    // stage Q tile, transposed to d-major
    #pragma unroll
    for (int qq = 0; qq < 4; ++qq) {
        const int d = c + 16*qq;
        const float4 v = *(const float4*)(Qg + (size_t)(q0 + r)*HD + d);
        QP[d+0][r] = v.x; QP[d+1][r] = v.y; QP[d+2][r] = v.z; QP[d+3][r] = v.w;
    }

    float m[4], l[4];
    #pragma unroll
    for (int i = 0; i < 4; ++i) { m[i] = -1e30f; l[i] = 0.f; }

    // ---------------- pass 1: scores + online softmax stats ----------------
    for (int kt = 0; kt < SS/64; ++kt) {
        __syncthreads();
        #pragma unroll
        for (int qq = 0; qq < 4; ++qq) {
            const int d = c + 16*qq;
            const float4 v = *(const float4*)(Kg + (size_t)(kt*64 + r)*HD + d);
            SB[d+0][r] = v.x; SB[d+1][r] = v.y; SB[d+2][r] = v.z; SB[d+3][r] = v.w;
        }
        __syncthreads();

        float s[4][4] = {{0.f,0.f,0.f,0.f},{0.f,0.f,0.f,0.f},
                         {0.f,0.f,0.f,0.f},{0.f,0.f,0.f,0.f}};
        #pragma unroll
        for (int kk = 0; kk < 64; ++kk) {
            const float4 av = *(const float4*)&QP[kk][ty<<2];
            const float4 bv = *(const float4*)&SB[kk][tx<<2];
            const float a[4] = {av.x, av.y, av.z, av.w};
            const float bb[4] = {bv.x, bv.y, bv.z, bv.w};
            #pragma unroll
            for (int i = 0; i < 4; ++i)
                #pragma unroll
                for (int j = 0; j < 4; ++j)
                    s[i][j] += a[i]*bb[j];
        }

        #pragma unroll
        for (int i = 0; i < 4; ++i) {
            float4 sv;
            sv.x = s[i][0]*0.125f; sv.y = s[i][1]*0.125f;
            sv.z = s[i][2]*0.125f; sv.w = s[i][3]*0.125f;
            *(float4*)(attn_bh + (size_t)(q0 + (ty<<2) + i)*SS + kt*64 + (tx<<2)) = sv;

            float tmax = fmaxf(fmaxf(sv.x, sv.y), fmaxf(sv.z, sv.w));
            #pragma unroll
            for (int msk = 1; msk < 16; msk <<= 1)
                tmax = fmaxf(tmax, __shfl_xor(tmax, msk, 64));
            const float mn = fmaxf(m[i], tmax);
            const float corr = __expf(m[i] - mn);
            float psum = __expf(sv.x - mn) + __expf(sv.y - mn)
                       + __expf(sv.z - mn) + __expf(sv.w - mn);
            #pragma unroll
            for (int msk = 1; msk < 16; msk <<= 1)
                psum += __shfl_xor(psum, msk, 64);
            l[i] = l[i]*corr + psum;
            m[i] = mn;
        }
    }

    if (tx == 0) {
        #pragma unroll
        for (int i = 0; i < 4; ++i) {
            m_s[(ty<<2)+i]  = m[i];
            il_s[(ty<<2)+i] = 1.f / l[i];
        }
    }
    __syncthreads();   // also guards QP/SB reuse across passes

    const float mr  = m_s[r];
    const float ilr = il_s[r];

    // ---------------- pass 2: normalize + write attn + PV ----------------
    float o[4][4] = {{0.f,0.f,0.f,0.f},{0.f,0.f,0.f,0.f},
                     {0.f,0.f,0.f,0.f},{0.f,0.f,0.f,0.f}};
    for (int kt = 0; kt < SS/64; ++kt) {
        #pragma unroll
        for (int qq = 0; qq < 4; ++qq) {           // stage V row-major
            const int d = c + 16*qq;
            *(float4*)&SB[r][d] = *(const float4*)(Vg + (size_t)(kt*64 + r)*HD + d);
        }
        #pragma unroll
        for (int qq = 0; qq < 4; ++qq) {           // normalize + transpose to P
            const int j = c + 16*qq;
            float* gp = attn_bh + (size_t)(q0 + r)*SS + kt*64 + j;
            const float4 sv = *(const float4*)gp;
            float4 pv;
            pv.x = __expf(sv.x - mr)*ilr; pv.y = __expf(sv.y - mr)*ilr;
            pv.z = __expf(sv.z - mr)*ilr; pv.w = __expf(sv.w - mr)*ilr;
            *(float4*)gp = pv;
            QP[j+0][r] = pv.x; QP[j+1][r] = pv.y;
            QP[j+2][r] = pv.z; QP[j+3][r] = pv.w;
        }
        __syncthreads();
        #pragma unroll
        for (int jj = 0; jj < 64; ++jj) {
            const float4 p4 = *(const float4*)&QP[jj][ty<<2];
            const float4 vv = *(const float4*)&SB[jj][tx<<2];
            const float p[4] = {p4.x, p4.y, p4.z, p4.w};
            const float vl[4] = {vv.x, vv.y, vv.z, vv.w};
            #pragma unroll
            for (int i = 0; i < 4; ++i)
                #pragma unroll
                for (int j = 0; j < 4; ++j)
                    o[i][j] += p[i]*vl[j];
        }
        __syncthreads();
    }

    #pragma unroll
    for (int i = 0; i < 4; ++i) {
        float4 ov; ov.x = o[i][0]; ov.y = o[i][1]; ov.z = o[i][2]; ov.w = o[i][3];
        *(float4*)(ctx + ((size_t)b*SS + q0 + (ty<<2) + i)*DM + h*HD + (tx<<2)) = ov;
    }
}

// ---------------------------------------------------------------------------
extern "C" void kernel_launch(void* const* d_in, const int* in_sizes, int n_in,
                              void* d_out, int out_size, void* d_ws, size_t ws_size,
                              hipStream_t stream)
{
    const float* q   = (const float*)d_in[0];
    const float* k   = (const float*)d_in[1];
    const float* v   = (const float*)d_in[2];
    const float* w_q = (const float*)d_in[3];
    const float* b_q = (const float*)d_in[4];
    const float* w_k = (const float*)d_in[5];
    const float* b_k = (const float*)d_in[6];
    const float* w_v = (const float*)d_in[7];
    const float* b_v = (const float*)d_in[8];
    const float* w_o = (const float*)d_in[9];
    const float* b_o = (const float*)d_in[10];

    float* out  = (float*)d_out;
    float* attn = out + (size_t)MROWS * DM;          // tuple part 2

    // workspace: qp|kp|vp (head-split [B,H,S,64]) + ctx [B,S,512] = 64 MB
    float* ws  = (float*)d_ws;
    float* qp  = ws;
    float* kp  = ws + (size_t)MROWS * DM;
    float* vp  = ws + 2*(size_t)MROWS * DM;
    float* ctx = ws + 3*(size_t)MROWS * DM;

    const dim3 gg(DM/64, MROWS/64);   // 8 x 128
    const dim3 tb(256);

    hipLaunchKernelGGL((gemm_xwt<0>), gg, tb, 0, stream, q, w_q, b_q, qp);
    hipLaunchKernelGGL((gemm_xwt<0>), gg, tb, 0, stream, k, w_k, b_k, kp);
    hipLaunchKernelGGL((gemm_xwt<0>), gg, tb, 0, stream, v, w_v, b_v, vp);
    hipLaunchKernelGGL(attn_kernel, dim3(SS/64, NH, BB), tb, 0, stream,
                       qp, kp, vp, attn, ctx);
    hipLaunchKernelGGL((gemm_xwt<1>), gg, tb, 0, stream, ctx, w_o, b_o, out);
}

// Round 5
// 805.821 us; speedup vs baseline: 1.6294x; 1.6294x over previous
//
#include <hip/hip_runtime.h>
#include <hip/hip_bf16.h>
#include <math.h>

#define DM 512
#define NH 8
#define HD 64
#define BB 4
#define SS 2048
#define MROWS (BB*SS)   // 8192

typedef short bf16x8 __attribute__((ext_vector_type(8)));
typedef float f32x4  __attribute__((ext_vector_type(4)));

#define MFMA16(a,b,c) __builtin_amdgcn_mfma_f32_16x16x32_bf16((a),(b),(c),0,0,0)

static __device__ __forceinline__ short f2bf(float x){
    __hip_bfloat16 h = __float2bfloat16(x);
    return *reinterpret_cast<short*>(&h);
}

// ---------------------------------------------------------------------------
// C = X @ W^T + bias (then *oscale).  X:[M,512] (fp32 or bf16), W:[512,512] fp32.
// OUT_BF16=1: bf16 head-split [B,H,S,64].  OUT_BF16=0: fp32 [M,512].
// 128x128 tile, BK=64, 4 waves (2x2 of 64x64), 16x16x32 bf16 MFMA.
// LDS tiles XOR-swizzled (chunk ^= row&7) -> conflict-free ds_read_b128.
template<int IN_F32, int OUT_BF16>
__global__ __launch_bounds__(256)
void gemm_mfma(const void* __restrict__ Xv, const float* __restrict__ W,
               const float* __restrict__ bias, void* __restrict__ Cv,
               float oscale)
{
    const int m0 = blockIdx.y * 128;
    const int n0 = blockIdx.x * 128;
    const int t  = threadIdx.x;
    const int w  = t >> 6;
    const int l  = t & 63;
    const int g  = l >> 4;
    const int lr = l & 15;
    const int wm0 = (w >> 1) * 64;
    const int wn0 = (w & 1) * 64;

    __shared__ short As[128*64];
    __shared__ short Bs[128*64];

    const f32x4 fzero = {0.f, 0.f, 0.f, 0.f};
    f32x4 acc[4][4];
    #pragma unroll
    for (int mi = 0; mi < 4; ++mi)
        #pragma unroll
        for (int ni = 0; ni < 4; ++ni) acc[mi][ni] = fzero;

    const float* Xf = (const float*)Xv;
    const short* Xb = (const short*)Xv;

    for (int k0 = 0; k0 < DM; k0 += 64) {
        __syncthreads();
        #pragma unroll
        for (int it = 0; it < 4; ++it) {
            const int idx = it*256 + t;
            const int row = idx >> 3, c = idx & 7;
            bf16x8 av, bv;
            if (IN_F32) {
                const float* p = Xf + (size_t)(m0+row)*DM + k0 + c*8;
                #pragma unroll
                for (int e = 0; e < 8; ++e) av[e] = f2bf(p[e]);
            } else {
                av = *(const bf16x8*)(Xb + (size_t)(m0+row)*DM + k0 + c*8);
            }
            {
                const float* p = W + (size_t)(n0+row)*DM + k0 + c*8;
                #pragma unroll
                for (int e = 0; e < 8; ++e) bv[e] = f2bf(p[e]);
            }
            *(bf16x8*)((char*)As + row*128 + ((c ^ (row & 7)) << 4)) = av;
            *(bf16x8*)((char*)Bs + row*128 + ((c ^ (row & 7)) << 4)) = bv;
        }
        __syncthreads();
        #pragma unroll
        for (int ks = 0; ks < 2; ++ks) {
            bf16x8 af[4], bw[4];
            #pragma unroll
            for (int mi = 0; mi < 4; ++mi) {
                const int row = wm0 + mi*16 + lr;
                af[mi] = *(const bf16x8*)((const char*)As + row*128 +
                                          (((ks*4 + g) ^ (lr & 7)) << 4));
            }
            #pragma unroll
            for (int ni = 0; ni < 4; ++ni) {
                const int row = wn0 + ni*16 + lr;
                bw[ni] = *(const bf16x8*)((const char*)Bs + row*128 +
                                          (((ks*4 + g) ^ (lr & 7)) << 4));
            }
            #pragma unroll
            for (int mi = 0; mi < 4; ++mi)
                #pragma unroll
                for (int ni = 0; ni < 4; ++ni)
                    acc[mi][ni] = MFMA16(af[mi], bw[ni], acc[mi][ni]);
        }
    }

    float bvals[4];
    #pragma unroll
    for (int ni = 0; ni < 4; ++ni) bvals[ni] = bias[n0 + wn0 + ni*16 + lr];

    if (OUT_BF16) {
        short* C = (short*)Cv;
        #pragma unroll
        for (int mi = 0; mi < 4; ++mi)
            #pragma unroll
            for (int jj = 0; jj < 4; ++jj) {
                const int m  = m0 + wm0 + mi*16 + g*4 + jj;
                const int bb = m >> 11, srow = m & (SS-1);
                #pragma unroll
                for (int ni = 0; ni < 4; ++ni) {
                    const int n  = n0 + wn0 + ni*16 + lr;
                    const int hh = n >> 6, d = n & 63;
                    const float v = (acc[mi][ni][jj] + bvals[ni]) * oscale;
                    C[(((size_t)(bb*NH + hh)*SS + srow) << 6) + d] = f2bf(v);
                }
            }
    } else {
        float* C = (float*)Cv;
        #pragma unroll
        for (int mi = 0; mi < 4; ++mi)
            #pragma unroll
            for (int jj = 0; jj < 4; ++jj) {
                const int m = m0 + wm0 + mi*16 + g*4 + jj;
                #pragma unroll
                for (int ni = 0; ni < 4; ++ni) {
                    const int n = n0 + wn0 + ni*16 + lr;
                    C[(size_t)m*DM + n] = acc[mi][ni][jj] + bvals[ni];
                }
            }
    }
}

// ---------------------------------------------------------------------------
// vp [B,H,S,64] -> vpt [B,H,64,S]   (writes merge in L2; no LDS needed)
__global__ __launch_bounds__(256)
void transpose_v(const short* __restrict__ vp, short* __restrict__ vpt)
{
    const int bid = blockIdx.x;
    const int st = bid & 31, bh = bid >> 5;
    const short* src = vp  + (size_t)bh*SS*HD + (size_t)st*64*HD;
    short*       dst = vpt + (size_t)bh*HD*SS + st*64;
    const int t = threadIdx.x;
    #pragma unroll
    for (int it = 0; it < 2; ++it) {
        const int idx = it*256 + t;
        const int k = idx >> 3, c = idx & 7;
        bf16x8 v = *(const bf16x8*)(src + k*HD + c*8);
        #pragma unroll
        for (int e = 0; e < 8; ++e)
            dst[(size_t)(c*8 + e)*SS + k] = v[e];
    }
}

// ---------------------------------------------------------------------------
// Attention, one (b,h,64-row q-tile) per block, 4 waves x 16 q-rows.
// qp is pre-scaled by 0.125*log2(e) -> softmax in exp2 domain (exact identity).
// pass 1: QK^T (MFMA) + online row max/sum (no spills).
// pass 2: recompute QK^T (bit-identical), p=exp2(s-m)/l -> write attn once,
//         p->bf16->LDS, PV via MFMA with pre-transposed V.
// R4 fix: ctx no longer aliases vp (graph-replay divergence on calls 2+);
//         explicit barrier between Ps write and PV read (insurance).
__global__ __launch_bounds__(256)
void attn_mfma(const short* __restrict__ qp, const short* __restrict__ kp,
               const short* __restrict__ vpt, float* __restrict__ attn,
               short* __restrict__ ctx)
{
    const int qt = blockIdx.x, h = blockIdx.y, b = blockIdx.z;
    const int q0 = qt * 64;
    const int t = threadIdx.x, w = t >> 6, l = t & 63, g = l >> 4, lr = l & 15;

    __shared__ short Ks[64*64];       // [key][d], swizzled
    __shared__ short Vs[64*64];       // [d][key], swizzled
    __shared__ short Ps[4][16*72];    // per-wave P, padded rows (144B)

    const size_t bh = (size_t)(b*NH + h);
    const short* Qg  = qp  + bh*SS*HD;
    const short* Kg  = kp  + bh*SS*HD;
    const short* Vtg = vpt + bh*HD*SS;
    float* attn_bh = attn + bh*SS*SS;

    // hoist Q fragments: A[m=lr][k=ks*32+g*8+j]
    bf16x8 aq[2];
    {
        const short* qrow = Qg + (size_t)(q0 + w*16 + lr)*HD;
        aq[0] = *(const bf16x8*)(qrow + g*8);
        aq[1] = *(const bf16x8*)(qrow + 32 + g*8);
    }

    const f32x4 fzero = {0.f, 0.f, 0.f, 0.f};
    float m_[4], l_[4];
    #pragma unroll
    for (int j = 0; j < 4; ++j) { m_[j] = -1e30f; l_[j] = 0.f; }

    // ---------------- pass 1: stats only ----------------
    for (int kt = 0; kt < SS/64; ++kt) {
        __syncthreads();
        #pragma unroll
        for (int it = 0; it < 2; ++it) {
            const int idx = it*256 + t;
            const int row = idx >> 3, c = idx & 7;
            bf16x8 kv = *(const bf16x8*)(Kg + (size_t)(kt*64 + row)*HD + c*8);
            *(bf16x8*)((char*)Ks + row*128 + ((c ^ (row & 7)) << 4)) = kv;
        }
        __syncthreads();
        f32x4 s[4];
        #pragma unroll
        for (int n4 = 0; n4 < 4; ++n4) s[n4] = fzero;
        #pragma unroll
        for (int ks = 0; ks < 2; ++ks)
            #pragma unroll
            for (int n4 = 0; n4 < 4; ++n4) {
                bf16x8 bk = *(const bf16x8*)((const char*)Ks + (n4*16 + lr)*128 +
                                             (((ks*4 + g) ^ (lr & 7)) << 4));
                s[n4] = MFMA16(aq[ks], bk, s[n4]);
            }
        #pragma unroll
        for (int j = 0; j < 4; ++j) {
            float mx = fmaxf(fmaxf(s[0][j], s[1][j]), fmaxf(s[2][j], s[3][j]));
            #pragma unroll
            for (int msk = 1; msk < 16; msk <<= 1)
                mx = fmaxf(mx, __shfl_xor(mx, msk, 64));
            const float mn = fmaxf(m_[j], mx);
            float ps = exp2f(s[0][j] - mn) + exp2f(s[1][j] - mn)
                     + exp2f(s[2][j] - mn) + exp2f(s[3][j] - mn);
            #pragma unroll
            for (int msk = 1; msk < 16; msk <<= 1)
                ps += __shfl_xor(ps, msk, 64);
            l_[j] = l_[j]*exp2f(m_[j] - mn) + ps;
            m_[j] = mn;
        }
    }
    float il[4];
    #pragma unroll
    for (int j = 0; j < 4; ++j) il[j] = 1.f / l_[j];

    f32x4 o[4];
    #pragma unroll
    for (int n4 = 0; n4 < 4; ++n4) o[n4] = fzero;

    // ---------------- pass 2: probs + PV ----------------
    for (int kt = 0; kt < SS/64; ++kt) {
        __syncthreads();
        #pragma unroll
        for (int it = 0; it < 2; ++it) {
            const int idx = it*256 + t;
            const int row = idx >> 3, c = idx & 7;
            bf16x8 kv = *(const bf16x8*)(Kg + (size_t)(kt*64 + row)*HD + c*8);
            *(bf16x8*)((char*)Ks + row*128 + ((c ^ (row & 7)) << 4)) = kv;
            bf16x8 vv = *(const bf16x8*)(Vtg + (size_t)row*SS + kt*64 + c*8);
            *(bf16x8*)((char*)Vs + row*128 + ((c ^ (row & 7)) << 4)) = vv;
        }
        __syncthreads();
        f32x4 s[4];
        #pragma unroll
        for (int n4 = 0; n4 < 4; ++n4) s[n4] = fzero;
        #pragma unroll
        for (int ks = 0; ks < 2; ++ks)
            #pragma unroll
            for (int n4 = 0; n4 < 4; ++n4) {
                bf16x8 bk = *(const bf16x8*)((const char*)Ks + (n4*16 + lr)*128 +
                                             (((ks*4 + g) ^ (lr & 7)) << 4));
                s[n4] = MFMA16(aq[ks], bk, s[n4]);
            }
        short* Pw = &Ps[w][0];
        #pragma unroll
        for (int j = 0; j < 4; ++j) {
            const int prow = g*4 + j;
            float* arow = attn_bh + (size_t)(q0 + w*16 + prow)*SS + kt*64;
            #pragma unroll
            for (int n4 = 0; n4 < 4; ++n4) {
                const float p = exp2f(s[n4][j] - m_[j]) * il[j];
                arow[n4*16 + lr] = p;
                Pw[prow*72 + n4*16 + lr] = f2bf(p);
            }
        }
        __syncthreads();   // R4: hard-order Ps writes before PV reads
        // PV: wave-local P
        #pragma unroll
        for (int ks = 0; ks < 2; ++ks) {
            bf16x8 pa = *(const bf16x8*)((const char*)Pw + lr*144 + ks*64 + g*16);
            #pragma unroll
            for (int n4 = 0; n4 < 4; ++n4) {
                bf16x8 bv = *(const bf16x8*)((const char*)Vs + (n4*16 + lr)*128 +
                                             (((ks*4 + g) ^ (lr & 7)) << 4));
                o[n4] = MFMA16(pa, bv, o[n4]);
            }
        }
    }

    // ctx bf16 [B,S,512]
    #pragma unroll
    for (int j = 0; j < 4; ++j) {
        const int qrow = q0 + w*16 + g*4 + j;
        short* crow = ctx + ((size_t)b*SS + qrow)*DM + h*HD;
        #pragma unroll
        for (int n4 = 0; n4 < 4; ++n4)
            crow[n4*16 + lr] = f2bf(o[n4][j]);
    }
}

// ---------------------------------------------------------------------------
extern "C" void kernel_launch(void* const* d_in, const int* in_sizes, int n_in,
                              void* d_out, int out_size, void* d_ws, size_t ws_size,
                              hipStream_t stream)
{
    const float* q   = (const float*)d_in[0];
    const float* k   = (const float*)d_in[1];
    const float* v   = (const float*)d_in[2];
    const float* w_q = (const float*)d_in[3];
    const float* b_q = (const float*)d_in[4];
    const float* w_k = (const float*)d_in[5];
    const float* b_k = (const float*)d_in[6];
    const float* w_v = (const float*)d_in[7];
    const float* b_v = (const float*)d_in[8];
    const float* w_o = (const float*)d_in[9];
    const float* b_o = (const float*)d_in[10];

    float* out  = (float*)d_out;
    float* attn = out + (size_t)MROWS * DM;

    // ws (bf16 as short): qp | kp | vp | vpt | ctx — 5 x 8.39 MB = 41.9 MB.
    // R4: ctx is its OWN region (aliasing vp broke graph-replay determinism).
    short* ws  = (short*)d_ws;
    const size_t SZ = (size_t)MROWS * DM;
    short* qp  = ws;
    short* kp  = ws + SZ;
    short* vp  = ws + 2*SZ;
    short* vpt = ws + 3*SZ;
    short* ctx = ws + 4*SZ;

    const float Q_SCALE = 0.125f * 1.44269504088896340736f; // fold 1/sqrt(64)*log2(e)
    const dim3 gg(DM/128, MROWS/128);   // 4 x 64
    const dim3 tb(256);

    hipLaunchKernelGGL((gemm_mfma<1,1>), gg, tb, 0, stream, q, w_q, b_q, qp, Q_SCALE);
    hipLaunchKernelGGL((gemm_mfma<1,1>), gg, tb, 0, stream, k, w_k, b_k, kp, 1.f);
    hipLaunchKernelGGL((gemm_mfma<1,1>), gg, tb, 0, stream, v, w_v, b_v, vp, 1.f);
    hipLaunchKernelGGL(transpose_v, dim3(BB*NH*32), tb, 0, stream, vp, vpt);
    hipLaunchKernelGGL(attn_mfma, dim3(SS/64, NH, BB), tb, 0, stream,
                       qp, kp, vpt, attn, ctx);
    hipLaunchKernelGGL((gemm_mfma<0,0>), gg, tb, 0, stream, ctx, w_o, b_o, out, 1.f);
}